// Round 15
// baseline (536.888 us; speedup 1.0000x reference)
//
#include <hip/hip_runtime.h>

#define LNUM 8
#define WD 128
#define BATCH 262144

typedef unsigned int u32;
typedef __attribute__((ext_vector_type(8))) short bf16x8;
typedef __attribute__((ext_vector_type(16))) float f32x16;

#define MFMA32 __builtin_amdgcn_mfma_f32_32x32x16_bf16
#define BC8(x) __builtin_bit_cast(bf16x8, x)

// packed f32x2 -> bf16x2 (single VALU op; validated R4+)
__device__ __forceinline__ u32 pk2(float x, float y){
  u32 r;
  asm("v_cvt_pk_bf16_f32 %0, %1, %2" : "=v"(r) : "v"(x), "v"(y));
  return r;
}

// ---------- weight-image staging (used by prep kernel & fallback) ----------
// W2: NATURAL row-major bf16, XOR-swizzled (j&15)<<2 at 4-dword granularity.
// mid1 A-frag (mt,kt) = ONE b128 at dword (kt*8 + hi*4) ^ sz, row j.
__device__ __forceinline__ void stage_Wnat32(const float* __restrict__ src, u32* dst, int tid){
  const int j = tid >> 1, h = tid & 1;
  const float* s = src + j * WD + h * 64;
  u32* drow = dst + j * 64;
  const u32 sz = (u32)((j & 15) << 2);
#pragma unroll
  for(int c = 0; c < 8; ++c){
    float4 f0 = *(const float4*)(s + c * 8);
    float4 f1 = *(const float4*)(s + c * 8 + 4);
    uint4 w;
    w.x = pk2(f0.x, f0.y); w.y = pk2(f0.z, f0.w);
    w.z = pk2(f1.x, f1.y); w.w = pk2(f1.z, f1.w);
    *(uint4*)(drow + (((u32)(h * 32 + c * 4)) ^ sz)) = w;
  }
}

// W3: PERMUTED for mid2's k-map k = 32b + (e&3) + 8*(2q+(e>>2)) + 4*hi.
// Chunk (b,q,hi) = 4 dwords at (b*2+q)*8 + hi*4: pairs from k-base 32b+16q+4hi:
// {base,base+1},{base+2,base+3},{base+8,base+9},{base+10,base+11}.
__device__ __forceinline__ void stage_Wperm32(const float* __restrict__ src, u32* dst, int tid){
  const int j = tid >> 1, h = tid & 1;
  const float* row = src + j * WD;
  u32* drow = dst + j * 64;
  const u32 sz = (u32)((j & 15) << 2);
#pragma unroll
  for(int bb = 0; bb < 2; ++bb){
    const int b = 2 * h + bb;
#pragma unroll
    for(int q = 0; q < 2; ++q)
#pragma unroll
      for(int hi2 = 0; hi2 < 2; ++hi2){
        const int base = 32 * b + 16 * q + 4 * hi2;
        uint4 w;
        w.x = pk2(row[base    ], row[base + 1 ]);
        w.y = pk2(row[base + 2], row[base + 3 ]);
        w.z = pk2(row[base + 8], row[base + 9 ]);
        w.w = pk2(row[base +10], row[base + 11]);
        *(uint4*)(drow + (((u32)((b * 2 + q) * 8 + hi2 * 4)) ^ sz)) = w;
      }
  }
}

// DMA a 16384-dword {W2|W3} slab into LDS, 8 waves (BLK=512). R11-proven.
__device__ __forceinline__ void stage_dma(const u32* __restrict__ g, u32* l, int wv, int lane){
#pragma unroll
  for(int it = 0; it < 8; ++it){
    const int o = wv * 2048 + it * 256;
    __builtin_amdgcn_global_load_lds(
        (const __attribute__((address_space(1))) u32*)(g + o + lane * 4),
        (__attribute__((address_space(3))) u32*)(l + o),
        16, 0, 0);
  }
}

// load 16 bias/weight values in the 32x32 C/D row pattern: j = base + (r&3)+8*(r>>2)+4*hi
#define LOAD_ROWVEC(dst0, dst1, dst2, dst3, ptr, mt) \
    const float4 dst0 = *(const float4*)((ptr) + (mt) * 32 + 4 * hi); \
    const float4 dst1 = *(const float4*)((ptr) + (mt) * 32 + 4 * hi + 8); \
    const float4 dst2 = *(const float4*)((ptr) + (mt) * 32 + 4 * hi + 16); \
    const float4 dst3 = *(const float4*)((ptr) + (mt) * 32 + 4 * hi + 24);

#define SET16(bi, q0, q1, q2, q3) do { \
    bi[0]=q0.x; bi[1]=q0.y; bi[2]=q0.z; bi[3]=q0.w; \
    bi[4]=q1.x; bi[5]=q1.y; bi[6]=q1.z; bi[7]=q1.w; \
    bi[8]=q2.x; bi[9]=q2.y; bi[10]=q2.z; bi[11]=q2.w; \
    bi[12]=q3.x; bi[13]=q3.y; bi[14]=q3.z; bi[15]=q3.w; \
  } while(0)

// stage-4 fold of finished mid2 tile mt (both sample-subtiles), split partials
#define FOLD32(mt) do { \
    LOAD_ROWVEC(f0, f1, f2, f3, W4, mt); \
    float* d0 = ((mt) & 1) ? &pb0 : &pa0; \
    float* d1 = ((mt) & 1) ? &pb1 : &pa1; \
    const f32x16 a0_ = aa[(mt)&1][0]; \
    const f32x16 a1_ = aa[(mt)&1][1]; \
    *d0 = fmaf(fmaxf(a0_[0],0.f),f0.x,fmaf(fmaxf(a0_[1],0.f),f0.y,fmaf(fmaxf(a0_[2],0.f),f0.z,fmaf(fmaxf(a0_[3],0.f),f0.w,*d0)))); \
    *d0 = fmaf(fmaxf(a0_[4],0.f),f1.x,fmaf(fmaxf(a0_[5],0.f),f1.y,fmaf(fmaxf(a0_[6],0.f),f1.z,fmaf(fmaxf(a0_[7],0.f),f1.w,*d0)))); \
    *d0 = fmaf(fmaxf(a0_[8],0.f),f2.x,fmaf(fmaxf(a0_[9],0.f),f2.y,fmaf(fmaxf(a0_[10],0.f),f2.z,fmaf(fmaxf(a0_[11],0.f),f2.w,*d0)))); \
    *d0 = fmaf(fmaxf(a0_[12],0.f),f3.x,fmaf(fmaxf(a0_[13],0.f),f3.y,fmaf(fmaxf(a0_[14],0.f),f3.z,fmaf(fmaxf(a0_[15],0.f),f3.w,*d0)))); \
    *d1 = fmaf(fmaxf(a1_[0],0.f),f0.x,fmaf(fmaxf(a1_[1],0.f),f0.y,fmaf(fmaxf(a1_[2],0.f),f0.z,fmaf(fmaxf(a1_[3],0.f),f0.w,*d1)))); \
    *d1 = fmaf(fmaxf(a1_[4],0.f),f1.x,fmaf(fmaxf(a1_[5],0.f),f1.y,fmaf(fmaxf(a1_[6],0.f),f1.z,fmaf(fmaxf(a1_[7],0.f),f1.w,*d1)))); \
    *d1 = fmaf(fmaxf(a1_[8],0.f),f2.x,fmaf(fmaxf(a1_[9],0.f),f2.y,fmaf(fmaxf(a1_[10],0.f),f2.z,fmaf(fmaxf(a1_[11],0.f),f2.w,*d1)))); \
    *d1 = fmaf(fmaxf(a1_[12],0.f),f3.x,fmaf(fmaxf(a1_[13],0.f),f3.y,fmaf(fmaxf(a1_[14],0.f),f3.z,fmaf(fmaxf(a1_[15],0.f),f3.w,*d1)))); \
  } while(0)

// Full 4-stage MLP for the wave's 64 samples using 32x32x16 MFMA.
// mid1: natural k-map (slot (hi,e) <-> k = kt*16+hi*8+e) on BOTH A (LDS) and
//   B (in-lane packed) -> permutation cancels. C/D map (m74/m101):
//   col=lane&31 (sample), row=(reg&3)+8*(reg>>2)+4*hi.
// mid2: k = j; lane already holds its sample's h-values for its hi-half rows ->
//   B dword i of K-step (b,q) = pk2(relu(d[8q+2i]), relu(d[8q+2i+1])) (own regs);
//   A = W3 pre-permuted to the same k-map (ONE b128 per (mt,b,q)).
__device__ __forceinline__ float mlp32x32(
    float u, const u32* __restrict__ W2lds, const u32* __restrict__ W3lds,
    const float* __restrict__ W1, const float* __restrict__ b1,
    const float* __restrict__ b2, const float* __restrict__ b3,
    const float* __restrict__ W4, int lane31, int hi, int lane)
{
  const float us0 = __shfl(u, lane31, 64);
  const float us1 = __shfl(u, 32 + lane31, 64);

  // ---- mid1 acc C-init = b2 ----
  f32x16 acc1[4][2];
#pragma unroll
  for(int mt = 0; mt < 4; ++mt){
    LOAD_ROWVEC(q0, q1, q2, q3, b2, mt);
    f32x16 bi;
    SET16(bi, q0, q1, q2, q3);
    acc1[mt][0] = bi; acc1[mt][1] = bi;
  }

  // ---- stage1 + mid1 (kt-outer; bv transient) ----
#pragma unroll
  for(int kt = 0; kt < 8; ++kt){
    const int kb = kt * 16 + hi * 8;
    const float4 wa = *(const float4*)(W1 + kb);
    const float4 wb = *(const float4*)(W1 + kb + 4);
    const float4 ga = *(const float4*)(b1 + kb);
    const float4 gb = *(const float4*)(b1 + kb + 4);
    uint4 bv0, bv1;
    bv0.x = pk2(fmaxf(fmaf(us0, wa.x, ga.x), 0.f), fmaxf(fmaf(us0, wa.y, ga.y), 0.f));
    bv0.y = pk2(fmaxf(fmaf(us0, wa.z, ga.z), 0.f), fmaxf(fmaf(us0, wa.w, ga.w), 0.f));
    bv0.z = pk2(fmaxf(fmaf(us0, wb.x, gb.x), 0.f), fmaxf(fmaf(us0, wb.y, gb.y), 0.f));
    bv0.w = pk2(fmaxf(fmaf(us0, wb.z, gb.z), 0.f), fmaxf(fmaf(us0, wb.w, gb.w), 0.f));
    bv1.x = pk2(fmaxf(fmaf(us1, wa.x, ga.x), 0.f), fmaxf(fmaf(us1, wa.y, ga.y), 0.f));
    bv1.y = pk2(fmaxf(fmaf(us1, wa.z, ga.z), 0.f), fmaxf(fmaf(us1, wa.w, ga.w), 0.f));
    bv1.z = pk2(fmaxf(fmaf(us1, wb.x, gb.x), 0.f), fmaxf(fmaf(us1, wb.y, gb.y), 0.f));
    bv1.w = pk2(fmaxf(fmaf(us1, wb.z, gb.z), 0.f), fmaxf(fmaf(us1, wb.w, gb.w), 0.f));
    __builtin_amdgcn_s_setprio(1);
#pragma unroll
    for(int mt = 0; mt < 4; ++mt){
      const int j = mt * 32 + lane31;
      const u32 sz = (u32)((j & 15) << 2);
      bf16x8 av = BC8(*(const uint4*)(W2lds + j * 64 + (((u32)(kt * 8 + hi * 4)) ^ sz)));
      acc1[mt][0] = MFMA32(av, BC8(bv0), acc1[mt][0], 0, 0, 0);
      acc1[mt][1] = MFMA32(av, BC8(bv1), acc1[mt][1], 0, 0, 0);
    }
    __builtin_amdgcn_s_setprio(0);
  }

  // ---- transition: relu + pack into mid2 B-operands (own registers) ----
  uint4 trq[4][2][2];   // [b][nt][q]
#pragma unroll
  for(int b = 0; b < 4; ++b)
#pragma unroll
    for(int nt = 0; nt < 2; ++nt)
#pragma unroll
      for(int q = 0; q < 2; ++q){
        const f32x16 a = acc1[b][nt];
        uint4 t;
        t.x = pk2(fmaxf(a[q*8+0], 0.f), fmaxf(a[q*8+1], 0.f));
        t.y = pk2(fmaxf(a[q*8+2], 0.f), fmaxf(a[q*8+3], 0.f));
        t.z = pk2(fmaxf(a[q*8+4], 0.f), fmaxf(a[q*8+5], 0.f));
        t.w = pk2(fmaxf(a[q*8+6], 0.f), fmaxf(a[q*8+7], 0.f));
        trq[b][nt][q] = t;
      }

  // ---- mid2 + stage-4 fold (pipelined 1 tile deep; split partials) ----
  f32x16 aa[2][2];
  float pa0 = 0.f, pb0 = 0.f, pa1 = 0.f, pb1 = 0.f;
#pragma unroll
  for(int mt = 0; mt < 4; ++mt){
    const int j2 = mt * 32 + lane31;
    const u32 sz = (u32)((j2 & 15) << 2);
    const u32* r = W3lds + j2 * 64;
    bf16x8 av[8];
#pragma unroll
    for(int c = 0; c < 8; ++c)
      av[c] = BC8(*(const uint4*)(r + (((u32)(c * 8 + hi * 4)) ^ sz)));
    LOAD_ROWVEC(q0, q1, q2, q3, b3, mt);
    f32x16 ci;
    SET16(ci, q0, q1, q2, q3);
    aa[mt & 1][0] = ci; aa[mt & 1][1] = ci;
    if(mt == 1) FOLD32(0);
    if(mt == 2) FOLD32(1);
    if(mt == 3) FOLD32(2);
    __builtin_amdgcn_s_setprio(1);
#pragma unroll
    for(int b = 0; b < 4; ++b)
#pragma unroll
      for(int q = 0; q < 2; ++q){
        aa[mt & 1][0] = MFMA32(av[b * 2 + q], BC8(trq[b][0][q]), aa[mt & 1][0], 0, 0, 0);
        aa[mt & 1][1] = MFMA32(av[b * 2 + q], BC8(trq[b][1][q]), aa[mt & 1][1], 0, 0, 0);
      }
    __builtin_amdgcn_s_setprio(0);
  }
  FOLD32(3);

  float p0 = pa0 + pb0, p1 = pa1 + pb1;
  p0 += __shfl_xor(p0, 32, 64);
  p1 += __shfl_xor(p1, 32, 64);
  return (lane & 32) ? p1 : p0;
}

// ---------------- preprocess: fp32 weights -> bf16 image in d_ws ----------------
// Slab for phase ph = 2*layer + isT at ph*16384: {W2 natural32 | W3 perm32}.
extern "C" __global__ void __launch_bounds__(256)
prep_kernel(const float* __restrict__ sW2, const float* __restrict__ sW3,
            const float* __restrict__ tW2, const float* __restrict__ tW3,
            u32* __restrict__ ws)
{
  const int b = blockIdx.x;                       // 32 = 8 layers x 4 matrices
  const int layer = b >> 2, which = b & 3;        // 0 sW2, 1 sW3, 2 tW2, 3 tW3
  const float* src = (which == 0 ? sW2 : which == 1 ? sW3 : which == 2 ? tW2 : tW3)
                     + layer * (WD * WD);
  u32* dst = ws + (size_t)(2 * layer + (which >> 1)) * 16384 + (size_t)(which & 1) * 8192;
  if(which & 1) stage_Wperm32(src, dst, threadIdx.x);
  else          stage_Wnat32 (src, dst, threadIdx.x);
}

// ---------------- main: 512 thr, 8 waves x 64 samples, DMA dbuf (R11 shell) ----------------
extern "C" __global__ void __launch_bounds__(512)
flow_dma(const float* __restrict__ x, const float* __restrict__ s_scale,
         const float* __restrict__ sW1, const float* __restrict__ sb1,
         const float* __restrict__ sb2, const float* __restrict__ sb3,
         const float* __restrict__ sW4, const float* __restrict__ sb4,
         const float* __restrict__ tW1, const float* __restrict__ tb1,
         const float* __restrict__ tb2, const float* __restrict__ tb3,
         const float* __restrict__ tW4, const float* __restrict__ tb4,
         const u32* __restrict__ wimg, float* __restrict__ out)
{
  __shared__ u32 Wbuf[2][16384];   // 128 KB: [buf][W2(8192) | W3(8192)]

  const int tid = threadIdx.x;
  const int lane = tid & 63, lane31 = lane & 31, hi = lane >> 5, wv = tid >> 6;
  const int gs = (int)blockIdx.x * 512 + tid;

  float2 ab = ((const float2*)x)[gs];
  float* scat = out + 2 * BATCH;
  float sv = 0.f;

  stage_dma(wimg, Wbuf[0], wv, lane);          // phase 0 slab

#pragma unroll 1
  for(int ph = 0; ph < 2 * LNUM; ++ph){
    const int i = ph >> 1, isT = ph & 1, parity = i & 1;
    asm volatile("s_waitcnt vmcnt(0)" ::: "memory");
    __syncthreads();                            // Wbuf[ph&1] fully landed
    if(ph < 2 * LNUM - 1)
      stage_dma(wimg + (size_t)(ph + 1) * 16384, Wbuf[(ph + 1) & 1], wv, lane);

    const int off = i * WD;
    const float u = parity ? ab.y : ab.x;
    const u32* W2l = Wbuf[ph & 1];
    const u32* W3l = Wbuf[ph & 1] + 8192;

    if(!isT){
      float pre = mlp32x32(u, W2l, W3l, sW1 + off, sb1 + off,
                           sb2 + off, sb3 + off, sW4 + off, lane31, hi, lane) + sb4[i];
      sv = s_scale[i] * tanhf(pre);
      scat[i * BATCH + gs] = sv;
    } else {
      float pre = mlp32x32(u, W2l, W3l, tW1 + off, tb1 + off,
                           tb2 + off, tb3 + off, tW4 + off, lane31, hi, lane) + tb4[i];
      const float tv = tanhf(pre);
      const float e = expf(sv);
      if(parity) ab.x = e * ab.x + tv; else ab.y = e * ab.y + tv;
    }
  }

  ((float2*)out)[gs] = ab;
}

// ---------------- fallback (ws too small): 256 thr, inline staging ----------------
extern "C" __global__ void __launch_bounds__(256, 2)
flow_fb(const float* __restrict__ x, const float* __restrict__ s_scale,
        const float* __restrict__ sW1, const float* __restrict__ sb1,
        const float* __restrict__ sW2, const float* __restrict__ sb2,
        const float* __restrict__ sW3, const float* __restrict__ sb3,
        const float* __restrict__ sW4, const float* __restrict__ sb4,
        const float* __restrict__ tW1, const float* __restrict__ tb1,
        const float* __restrict__ tW2, const float* __restrict__ tb2,
        const float* __restrict__ tW3, const float* __restrict__ tb3,
        const float* __restrict__ tW4, const float* __restrict__ tb4,
        float* __restrict__ out)
{
  __shared__ u32 Wlds[2][8192];

  const int tid = threadIdx.x;
  const int lane = tid & 63, lane31 = lane & 31, hi = lane >> 5;
  const int gs = (int)blockIdx.x * 256 + tid;

  float2 ab = ((const float2*)x)[gs];
  float* scat = out + 2 * BATCH;

#pragma unroll 1
  for(int i = 0; i < LNUM; ++i){
    const int parity = i & 1;
    const float sc = s_scale[i];
    const int off = i * WD, offW = i * (WD * WD);

    __syncthreads();
    stage_Wnat32 (sW2 + offW, Wlds[0], tid);
    stage_Wperm32(sW3 + offW, Wlds[1], tid);
    __syncthreads();
    const float u = parity ? ab.y : ab.x;
    float preS = mlp32x32(u, Wlds[0], Wlds[1], sW1 + off, sb1 + off,
                          sb2 + off, sb3 + off, sW4 + off, lane31, hi, lane) + sb4[i];
    const float sv = sc * tanhf(preS);
    scat[i * BATCH + gs] = sv;

    __syncthreads();
    stage_Wnat32 (tW2 + offW, Wlds[0], tid);
    stage_Wperm32(tW3 + offW, Wlds[1], tid);
    __syncthreads();
    float preT = mlp32x32(u, Wlds[0], Wlds[1], tW1 + off, tb1 + off,
                          tb2 + off, tb3 + off, tW4 + off, lane31, hi, lane) + tb4[i];
    const float tv = tanhf(preT);
    const float e = expf(sv);
    if(parity) ab.x = e * ab.x + tv; else ab.y = e * ab.y + tv;
  }

  ((float2*)out)[gs] = ab;
}

extern "C" void kernel_launch(void* const* d_in, const int* in_sizes, int n_in,
                              void* d_out, int out_size, void* d_ws, size_t ws_size,
                              hipStream_t stream) {
  (void)in_sizes; (void)n_in; (void)out_size;
  const float* p[18];
  for(int k = 0; k < 18; ++k) p[k] = (const float*)d_in[k];

  const size_t need = (size_t)32 * 8192 * 4;   // 1 MiB bf16 weight image
  if(ws_size >= need){
    u32* ws = (u32*)d_ws;
    hipLaunchKernelGGL(prep_kernel, dim3(32), dim3(256), 0, stream,
                       p[4], p[6], p[12], p[14], ws);
    hipLaunchKernelGGL(flow_dma, dim3(BATCH / 512), dim3(512), 0, stream,
                       p[0], p[1], p[2], p[3], p[5], p[7], p[8], p[9],
                       p[10], p[11], p[13], p[15], p[16], p[17],
                       (const u32*)ws, (float*)d_out);
  } else {
    hipLaunchKernelGGL(flow_fb, dim3(BATCH / 256), dim3(256), 0, stream,
                       p[0], p[1], p[2], p[3], p[4], p[5], p[6], p[7], p[8], p[9],
                       p[10], p[11], p[12], p[13], p[14], p[15], p[16], p[17],
                       (float*)d_out);
  }
}

// Round 16
// 277.579 us; speedup vs baseline: 1.9342x; 1.9342x over previous
//
#include <hip/hip_runtime.h>

#define LNUM 8
#define WD 128
#define BATCH 262144

typedef unsigned int u32;
typedef __attribute__((ext_vector_type(8))) short bf16x8;
typedef __attribute__((ext_vector_type(4))) float f32x4;

// packed f32x2 -> bf16x2 (single VALU op; validated R4+)
__device__ __forceinline__ u32 pk2(float x, float y){
  u32 r;
  asm("v_cvt_pk_bf16_f32 %0, %1, %2" : "=v"(r) : "v"(x), "v"(y));
  return r;
}

__device__ __forceinline__ void fence(){ __builtin_amdgcn_sched_barrier(0); }

// NATURAL-order W image (mid1 k-map). Row-major bf16, XOR-swizzled 4-dword.
// 256 threads: row j=t>>1, half h=t&1. Validated R2+.
__device__ __forceinline__ void stage_Wnat(const float* __restrict__ src, u32* dst, int tid){
  const int j = tid >> 1, h = tid & 1;
  const float* s = src + j * WD + h * 64;
  u32* drow = dst + j * 64;
  const int base = h * 32;
  const u32 sz = (u32)((j & 7) << 2);
#pragma unroll
  for(int c = 0; c < 8; ++c){
    float4 f0 = *(const float4*)(s + c * 8);
    float4 f1 = *(const float4*)(s + c * 8 + 4);
    uint4 w;
    w.x = pk2(f0.x, f0.y); w.y = pk2(f0.z, f0.w);
    w.z = pk2(f1.x, f1.y); w.w = pk2(f1.z, f1.w);
    *(uint4*)(drow + (((u32)(base + c * 4)) ^ sz)) = w;
  }
}

// PERMUTED fragment-contiguous W image (mid2 k-map
// slot(lg,e) <-> k = kt*32+(e>>2)*16+lg*4+(e&3)): A-fragment for (lg,kt) is
// ONE b128 at dword (kt*16+lg*4)^sz. Validated R9+.
__device__ __forceinline__ void stage_Wperm(const float* __restrict__ src, u32* dst, int tid){
  const int j = tid >> 1, h = tid & 1;
  const float* srow = src + j * WD;
  u32* drow = dst + j * 64;
  const u32 sz = (u32)((j & 7) << 2);
#pragma unroll
  for(int kk = 0; kk < 2; ++kk){
    const int kt = 2 * h + kk;
#pragma unroll
    for(int g = 0; g < 4; ++g){
      float4 f0 = *(const float4*)(srow + kt * 32 + g * 4);
      float4 f1 = *(const float4*)(srow + kt * 32 + 16 + g * 4);
      uint4 w;
      w.x = pk2(f0.x, f0.y); w.y = pk2(f0.z, f0.w);
      w.z = pk2(f1.x, f1.y); w.w = pk2(f1.z, f1.w);
      *(uint4*)(drow + (((u32)(kt * 16 + g * 4)) ^ sz)) = w;
    }
  }
}

// DMA a 16384-dword {W2|W3} slab into LDS with 4 waves (BLK=256).
__device__ __forceinline__ void stage_dma4(const u32* __restrict__ g, u32* l, int wv, int lane){
#pragma unroll
  for(int it = 0; it < 16; ++it){
    const int o = wv * 4096 + it * 256;
    __builtin_amdgcn_global_load_lds(
        (const __attribute__((address_space(1))) u32*)(g + o + lane * 4),
        (__attribute__((address_space(3))) u32*)(l + o),
        16, 0, 0);
  }
}

// Full 4-stage MLP for the wave's 64 samples — BYTE-IDENTICAL to R11 (271 us,
// absmax .03125, VGPR 120, no spill). mid1: natural k-map, A = b128 natural
// LDS, C-init = b2. mid2: permuted k-map, B = lane's OWN tr dwords, A = b128
// fragment-contiguous LDS, C-init = b3.
__device__ __forceinline__ float mlp_full(
    float u, const u32* __restrict__ W2lds, const u32* __restrict__ W3lds,
    const float* __restrict__ W1, const float* __restrict__ b1,
    const float* __restrict__ b2, const float* __restrict__ b3,
    const float* __restrict__ W4, int lm, int lg)
{
  float ust[4];
#pragma unroll
  for(int st = 0; st < 4; ++st) ust[st] = __shfl(u, st * 16 + lm, 64);

  f32x4 acc1[8][4];
#pragma unroll
  for(int jt = 0; jt < 8; ++jt){
    const float4 bb = *(const float4*)(b2 + jt * 16 + lg * 4);
    const f32x4 binit = {bb.x, bb.y, bb.z, bb.w};
#pragma unroll
    for(int st = 0; st < 4; ++st) acc1[jt][st] = binit;
  }

  // ---- stage1 (VALU, transient bv[4]) + mid1 (natural k-map, kt-outer) ----
#pragma unroll
  for(int kt = 0; kt < 4; ++kt){
    const int ko = kt * 32 + lg * 8;
    const float4 w1a = *(const float4*)(W1 + ko);
    const float4 w1b = *(const float4*)(W1 + ko + 4);
    const float4 g1a = *(const float4*)(b1 + ko);
    const float4 g1b = *(const float4*)(b1 + ko + 4);
    bf16x8 bv[4];
#pragma unroll
    for(int st = 0; st < 4; ++st){
      const float uv = ust[st];
      uint4 pk;
      pk.x = pk2(fmaxf(fmaf(uv, w1a.x, g1a.x), 0.f), fmaxf(fmaf(uv, w1a.y, g1a.y), 0.f));
      pk.y = pk2(fmaxf(fmaf(uv, w1a.z, g1a.z), 0.f), fmaxf(fmaf(uv, w1a.w, g1a.w), 0.f));
      pk.z = pk2(fmaxf(fmaf(uv, w1b.x, g1b.x), 0.f), fmaxf(fmaf(uv, w1b.y, g1b.y), 0.f));
      pk.w = pk2(fmaxf(fmaf(uv, w1b.z, g1b.z), 0.f), fmaxf(fmaf(uv, w1b.w, g1b.w), 0.f));
      bv[st] = __builtin_bit_cast(bf16x8, pk);
    }
    const u32 kdw = (u32)(kt * 16 + lg * 4);
#pragma unroll
    for(int jt = 0; jt < 8; ++jt){
      const int j = lm + 16 * jt;
      bf16x8 av = __builtin_bit_cast(bf16x8,
          *(const uint4*)(W2lds + j * 64 + (kdw ^ (u32)((j & 7) << 2))));
#pragma unroll
      for(int st = 0; st < 4; ++st)
        acc1[jt][st] = __builtin_amdgcn_mfma_f32_16x16x32_bf16(av, bv[st], acc1[jt][st], 0, 0, 0);
    }
  }
  fence();

  // ---- transition: relu + pack ----
  u32 tr[8][4][2];
#pragma unroll
  for(int jt = 0; jt < 8; ++jt)
#pragma unroll
    for(int st = 0; st < 4; ++st){
      tr[jt][st][0] = pk2(fmaxf(acc1[jt][st][0], 0.f), fmaxf(acc1[jt][st][1], 0.f));
      tr[jt][st][1] = pk2(fmaxf(acc1[jt][st][2], 0.f), fmaxf(acc1[jt][st][3], 0.f));
    }
  fence();

  // ---- mid2 (permuted k-map; B = own tr; A = 1x b128) + stage-4 fold ----
  float p0 = 0.f, p1 = 0.f, p2 = 0.f, p3 = 0.f;
#pragma unroll
  for(int jt = 0; jt < 8; ++jt){
    const int j = lm + 16 * jt;
    const u32 sz = (u32)((j & 7) << 2);
    const u32* r = W3lds + j * 64;
    const float4 bc = *(const float4*)(b3 + jt * 16 + lg * 4);
    const f32x4 cinit = {bc.x, bc.y, bc.z, bc.w};
    f32x4 a0 = cinit, a1 = cinit, a2 = cinit, a3 = cinit;
#pragma unroll
    for(int kt = 0; kt < 4; ++kt){
      bf16x8 av = __builtin_bit_cast(bf16x8,
          *(const uint4*)(r + (((u32)(kt * 16 + lg * 4)) ^ sz)));
      uint4 q0; q0.x = tr[2*kt][0][0]; q0.y = tr[2*kt][0][1];
      q0.z = tr[2*kt+1][0][0]; q0.w = tr[2*kt+1][0][1];
      uint4 q1; q1.x = tr[2*kt][1][0]; q1.y = tr[2*kt][1][1];
      q1.z = tr[2*kt+1][1][0]; q1.w = tr[2*kt+1][1][1];
      uint4 q2; q2.x = tr[2*kt][2][0]; q2.y = tr[2*kt][2][1];
      q2.z = tr[2*kt+1][2][0]; q2.w = tr[2*kt+1][2][1];
      uint4 q3; q3.x = tr[2*kt][3][0]; q3.y = tr[2*kt][3][1];
      q3.z = tr[2*kt+1][3][0]; q3.w = tr[2*kt+1][3][1];
      a0 = __builtin_amdgcn_mfma_f32_16x16x32_bf16(av, __builtin_bit_cast(bf16x8, q0), a0, 0, 0, 0);
      a1 = __builtin_amdgcn_mfma_f32_16x16x32_bf16(av, __builtin_bit_cast(bf16x8, q1), a1, 0, 0, 0);
      a2 = __builtin_amdgcn_mfma_f32_16x16x32_bf16(av, __builtin_bit_cast(bf16x8, q2), a2, 0, 0, 0);
      a3 = __builtin_amdgcn_mfma_f32_16x16x32_bf16(av, __builtin_bit_cast(bf16x8, q3), a3, 0, 0, 0);
    }
    const float4 wc = *(const float4*)(W4 + jt * 16 + lg * 4);
    p0 = fmaf(fmaxf(a0[0], 0.f), wc.x, p0); p0 = fmaf(fmaxf(a0[1], 0.f), wc.y, p0);
    p0 = fmaf(fmaxf(a0[2], 0.f), wc.z, p0); p0 = fmaf(fmaxf(a0[3], 0.f), wc.w, p0);
    p1 = fmaf(fmaxf(a1[0], 0.f), wc.x, p1); p1 = fmaf(fmaxf(a1[1], 0.f), wc.y, p1);
    p1 = fmaf(fmaxf(a1[2], 0.f), wc.z, p1); p1 = fmaf(fmaxf(a1[3], 0.f), wc.w, p1);
    p2 = fmaf(fmaxf(a2[0], 0.f), wc.x, p2); p2 = fmaf(fmaxf(a2[1], 0.f), wc.y, p2);
    p2 = fmaf(fmaxf(a2[2], 0.f), wc.z, p2); p2 = fmaf(fmaxf(a2[3], 0.f), wc.w, p2);
    p3 = fmaf(fmaxf(a3[0], 0.f), wc.x, p3); p3 = fmaf(fmaxf(a3[1], 0.f), wc.y, p3);
    p3 = fmaf(fmaxf(a3[2], 0.f), wc.z, p3); p3 = fmaf(fmaxf(a3[3], 0.f), wc.w, p3);
  }
  fence();
  p0 += __shfl_xor(p0, 16, 64); p0 += __shfl_xor(p0, 32, 64);
  p1 += __shfl_xor(p1, 16, 64); p1 += __shfl_xor(p1, 32, 64);
  p2 += __shfl_xor(p2, 16, 64); p2 += __shfl_xor(p2, 32, 64);
  p3 += __shfl_xor(p3, 16, 64); p3 += __shfl_xor(p3, 32, 64);
  return (lg == 0) ? p0 : (lg == 1) ? p1 : (lg == 2) ? p2 : p3;
}

// ---------------- preprocess: fp32 weights -> bf16 image in d_ws ----------------
// Layout (R11-proven): slab for phase ph = 2*layer+isT at ph*16384 dwords,
// first 8192 = W2 natural, second 8192 = W3 permuted.
extern "C" __global__ void __launch_bounds__(256)
prep_kernel(const float* __restrict__ sW2, const float* __restrict__ sW3,
            const float* __restrict__ tW2, const float* __restrict__ tW3,
            u32* __restrict__ ws)
{
  const int b = blockIdx.x;                       // 32 = 8 layers x 4 matrices
  const int layer = b >> 2, which = b & 3;        // 0 sW2, 1 sW3, 2 tW2, 3 tW3
  const float* src = (which == 0 ? sW2 : which == 1 ? sW3 : which == 2 ? tW2 : tW3)
                     + layer * (WD * WD);
  u32* dst = ws + b * 8192;
  if(which & 1) stage_Wperm(src, dst, threadIdx.x);
  else          stage_Wnat (src, dst, threadIdx.x);
}

// ---------------- main: 256 thr, 4 waves, SINGLE 64 KB buffer ----------------
// 2 blocks/CU (LDS 2x64 KB) with independent barriers -> the 2 waves/SIMD come
// from DIFFERENT blocks and decorrelate (one block's VALU/drain phase overlaps
// the other block's MFMA phase).
extern "C" __global__ void __launch_bounds__(256, 2)
flow_dma(const float* __restrict__ x, const float* __restrict__ s_scale,
         const float* __restrict__ sW1, const float* __restrict__ sb1,
         const float* __restrict__ sb2, const float* __restrict__ sb3,
         const float* __restrict__ sW4, const float* __restrict__ sb4,
         const float* __restrict__ tW1, const float* __restrict__ tb1,
         const float* __restrict__ tb2, const float* __restrict__ tb3,
         const float* __restrict__ tW4, const float* __restrict__ tb4,
         const u32* __restrict__ wimg, float* __restrict__ out)
{
  __shared__ u32 Wbuf[16384];   // 64 KB: {W2(8192) | W3(8192)} current phase

  const int tid = threadIdx.x;
  const int lane = tid & 63, lg = lane >> 4, lm = lane & 15, wv = tid >> 6;
  const int gs = (int)blockIdx.x * 256 + tid;

  float2 ab = ((const float2*)x)[gs];
  float* scat = out + 2 * BATCH;
  float sv = 0.f;

#pragma unroll 1
  for(int ph = 0; ph < 2 * LNUM; ++ph){
    const int i = ph >> 1, isT = ph & 1, parity = i & 1;

    __syncthreads();                               // all waves done reading Wbuf
    stage_dma4(wimg + (size_t)ph * 16384, Wbuf, wv, lane);
    asm volatile("s_waitcnt vmcnt(0)" ::: "memory");
    __syncthreads();                               // slab landed for all waves

    const int off = i * WD;
    const float u = parity ? ab.y : ab.x;
    const u32* W2l = Wbuf;
    const u32* W3l = Wbuf + 8192;

    if(!isT){
      float pre = mlp_full(u, W2l, W3l, sW1 + off, sb1 + off,
                           sb2 + off, sb3 + off, sW4 + off, lm, lg) + sb4[i];
      sv = s_scale[i] * tanhf(pre);
      scat[i * BATCH + gs] = sv;
    } else {
      float pre = mlp_full(u, W2l, W3l, tW1 + off, tb1 + off,
                           tb2 + off, tb3 + off, tW4 + off, lm, lg) + tb4[i];
      const float tv = tanhf(pre);
      const float e = expf(sv);
      if(parity) ab.x = e * ab.x + tv; else ab.y = e * ab.y + tv;
    }
  }

  ((float2*)out)[gs] = ab;
}

// ---------------- fallback (ws too small): 256 thr, inline staging (R11) ----------------
extern "C" __global__ void __launch_bounds__(256, 2)
flow_fb(const float* __restrict__ x, const float* __restrict__ s_scale,
        const float* __restrict__ sW1, const float* __restrict__ sb1,
        const float* __restrict__ sW2, const float* __restrict__ sb2,
        const float* __restrict__ sW3, const float* __restrict__ sb3,
        const float* __restrict__ sW4, const float* __restrict__ sb4,
        const float* __restrict__ tW1, const float* __restrict__ tb1,
        const float* __restrict__ tW2, const float* __restrict__ tb2,
        const float* __restrict__ tW3, const float* __restrict__ tb3,
        const float* __restrict__ tW4, const float* __restrict__ tb4,
        float* __restrict__ out)
{
  __shared__ u32 Wlds[2][8192];

  const int tid = threadIdx.x;
  const int lane = tid & 63, lg = lane >> 4, lm = lane & 15;
  const int gs = (int)blockIdx.x * 256 + tid;

  float2 ab = ((const float2*)x)[gs];
  float* scat = out + 2 * BATCH;

#pragma unroll 1
  for(int i = 0; i < LNUM; ++i){
    const int parity = i & 1;
    const float sc = s_scale[i];
    const int off = i * WD, offW = i * (WD * WD);

    __syncthreads();
    stage_Wnat (sW2 + offW, Wlds[0], tid);
    stage_Wperm(sW3 + offW, Wlds[1], tid);
    __syncthreads();
    const float u = parity ? ab.y : ab.x;
    float preS = mlp_full(u, Wlds[0], Wlds[1], sW1 + off, sb1 + off,
                          sb2 + off, sb3 + off, sW4 + off, lm, lg) + sb4[i];
    const float sv = sc * tanhf(preS);
    scat[i * BATCH + gs] = sv;

    __syncthreads();
    stage_Wnat (tW2 + offW, Wlds[0], tid);
    stage_Wperm(tW3 + offW, Wlds[1], tid);
    __syncthreads();
    float preT = mlp_full(u, Wlds[0], Wlds[1], tW1 + off, tb1 + off,
                          tb2 + off, tb3 + off, tW4 + off, lm, lg) + tb4[i];
    const float tv = tanhf(preT);
    const float e = expf(sv);
    if(parity) ab.x = e * ab.x + tv; else ab.y = e * ab.y + tv;
  }

  ((float2*)out)[gs] = ab;
}

extern "C" void kernel_launch(void* const* d_in, const int* in_sizes, int n_in,
                              void* d_out, int out_size, void* d_ws, size_t ws_size,
                              hipStream_t stream) {
  (void)in_sizes; (void)n_in; (void)out_size;
  const float* p[18];
  for(int k = 0; k < 18; ++k) p[k] = (const float*)d_in[k];

  const size_t need = (size_t)32 * 8192 * 4;   // 1 MiB bf16 weight image
  if(ws_size >= need){
    u32* ws = (u32*)d_ws;
    hipLaunchKernelGGL(prep_kernel, dim3(32), dim3(256), 0, stream,
                       p[4], p[6], p[12], p[14], ws);
    hipLaunchKernelGGL(flow_dma, dim3(BATCH / 256), dim3(256), 0, stream,
                       p[0], p[1], p[2], p[3], p[5], p[7], p[8], p[9],
                       p[10], p[11], p[13], p[15], p[16], p[17],
                       (const u32*)ws, (float*)d_out);
  } else {
    hipLaunchKernelGGL(flow_fb, dim3(BATCH / 256), dim3(256), 0, stream,
                       p[0], p[1], p[2], p[3], p[4], p[5], p[6], p[7], p[8], p[9],
                       p[10], p[11], p[12], p[13], p[14], p[15], p[16], p[17],
                       (float*)d_out);
  }
}

// Round 17
// 271.251 us; speedup vs baseline: 1.9793x; 1.0233x over previous
//
#include <hip/hip_runtime.h>

#define LNUM 8
#define WD 128
#define BATCH 262144

typedef unsigned int u32;
typedef __attribute__((ext_vector_type(8))) short bf16x8;
typedef __attribute__((ext_vector_type(4))) float f32x4;

// packed f32x2 -> bf16x2 (single VALU op; validated R4+)
__device__ __forceinline__ u32 pk2(float x, float y){
  u32 r;
  asm("v_cvt_pk_bf16_f32 %0, %1, %2" : "=v"(r) : "v"(x), "v"(y));
  return r;
}

__device__ __forceinline__ void fence(){ __builtin_amdgcn_sched_barrier(0); }

// NATURAL-order W image (for mid1's natural k-map): row-major bf16,
// XOR-swizzled at 4-dword granularity. dst may be LDS or global (generic).
// 256 threads: row j=t>>1, half h=t&1. Validated R2/R3/R10.
__device__ __forceinline__ void stage_Wnat(const float* __restrict__ src, u32* dst, int tid){
  const int j = tid >> 1, h = tid & 1;
  const float* s = src + j * WD + h * 64;
  u32* drow = dst + j * 64;
  const int base = h * 32;
  const u32 sz = (u32)((j & 7) << 2);
#pragma unroll
  for(int c = 0; c < 8; ++c){
    float4 f0 = *(const float4*)(s + c * 8);
    float4 f1 = *(const float4*)(s + c * 8 + 4);
    uint4 w;
    w.x = pk2(f0.x, f0.y); w.y = pk2(f0.z, f0.w);
    w.z = pk2(f1.x, f1.y); w.w = pk2(f1.z, f1.w);
    *(uint4*)(drow + (((u32)(base + c * 4)) ^ sz)) = w;
  }
}

// PERMUTED fragment-contiguous W image (for mid2's permuted k-map
// slot(lg,e) <-> k = kt*32+(e>>2)*16+lg*4+(e&3)): A-fragment for (lg,kt) is
// ONE b128 at dword (kt*16+lg*4)^sz. Validated R9/R10.
__device__ __forceinline__ void stage_Wperm(const float* __restrict__ src, u32* dst, int tid){
  const int j = tid >> 1, h = tid & 1;
  const float* srow = src + j * WD;
  u32* drow = dst + j * 64;
  const u32 sz = (u32)((j & 7) << 2);
#pragma unroll
  for(int kk = 0; kk < 2; ++kk){
    const int kt = 2 * h + kk;
#pragma unroll
    for(int g = 0; g < 4; ++g){
      float4 f0 = *(const float4*)(srow + kt * 32 + g * 4);
      float4 f1 = *(const float4*)(srow + kt * 32 + 16 + g * 4);
      uint4 w;
      w.x = pk2(f0.x, f0.y); w.y = pk2(f0.z, f0.w);
      w.z = pk2(f1.x, f1.y); w.w = pk2(f1.z, f1.w);
      *(uint4*)(drow + (((u32)(kt * 16 + g * 4)) ^ sz)) = w;
    }
  }
}

// DMA a 16384-dword (two-matrix) slab from the preprocessed global image into
// LDS. global_load_lds: per-lane GLOBAL src, wave-uniform LDS base + lane*16.
__device__ __forceinline__ void stage_dma(const u32* __restrict__ g, u32* l, int wv, int lane){
#pragma unroll
  for(int it = 0; it < 8; ++it){
    const int o = wv * 2048 + it * 256;
    __builtin_amdgcn_global_load_lds(
        (const __attribute__((address_space(1))) u32*)(g + o + lane * 4),
        (__attribute__((address_space(3))) u32*)(l + o),
        16, 0, 0);
  }
}

// Full 4-stage MLP for the wave's 64 samples (R10's proven-clean shape,
// byte-identical numerics). mid1: natural k-map, A = b128 natural LDS,
// C-init = b2. mid2: permuted k-map, B = lane's OWN tr dwords, A = b128
// fragment-contiguous LDS, C-init = b3. Validated R10 (443 us, absmax .03125).
__device__ __forceinline__ float mlp_full(
    float u, const u32* __restrict__ W2lds, const u32* __restrict__ W3lds,
    const float* __restrict__ W1, const float* __restrict__ b1,
    const float* __restrict__ b2, const float* __restrict__ b3,
    const float* __restrict__ W4, int lm, int lg)
{
  float ust[4];
#pragma unroll
  for(int st = 0; st < 4; ++st) ust[st] = __shfl(u, st * 16 + lm, 64);

  f32x4 acc1[8][4];
#pragma unroll
  for(int jt = 0; jt < 8; ++jt){
    const float4 bb = *(const float4*)(b2 + jt * 16 + lg * 4);
    const f32x4 binit = {bb.x, bb.y, bb.z, bb.w};
#pragma unroll
    for(int st = 0; st < 4; ++st) acc1[jt][st] = binit;
  }

  // ---- stage1 (VALU, transient bv[4]) + mid1 (natural k-map, kt-outer) ----
#pragma unroll
  for(int kt = 0; kt < 4; ++kt){
    const int ko = kt * 32 + lg * 8;
    const float4 w1a = *(const float4*)(W1 + ko);
    const float4 w1b = *(const float4*)(W1 + ko + 4);
    const float4 g1a = *(const float4*)(b1 + ko);
    const float4 g1b = *(const float4*)(b1 + ko + 4);
    bf16x8 bv[4];
#pragma unroll
    for(int st = 0; st < 4; ++st){
      const float uv = ust[st];
      uint4 pk;
      pk.x = pk2(fmaxf(fmaf(uv, w1a.x, g1a.x), 0.f), fmaxf(fmaf(uv, w1a.y, g1a.y), 0.f));
      pk.y = pk2(fmaxf(fmaf(uv, w1a.z, g1a.z), 0.f), fmaxf(fmaf(uv, w1a.w, g1a.w), 0.f));
      pk.z = pk2(fmaxf(fmaf(uv, w1b.x, g1b.x), 0.f), fmaxf(fmaf(uv, w1b.y, g1b.y), 0.f));
      pk.w = pk2(fmaxf(fmaf(uv, w1b.z, g1b.z), 0.f), fmaxf(fmaf(uv, w1b.w, g1b.w), 0.f));
      bv[st] = __builtin_bit_cast(bf16x8, pk);
    }
    const u32 kdw = (u32)(kt * 16 + lg * 4);
#pragma unroll
    for(int jt = 0; jt < 8; ++jt){
      const int j = lm + 16 * jt;
      bf16x8 av = __builtin_bit_cast(bf16x8,
          *(const uint4*)(W2lds + j * 64 + (kdw ^ (u32)((j & 7) << 2))));
#pragma unroll
      for(int st = 0; st < 4; ++st)
        acc1[jt][st] = __builtin_amdgcn_mfma_f32_16x16x32_bf16(av, bv[st], acc1[jt][st], 0, 0, 0);
    }
  }
  fence();

  // ---- transition: relu + pack ----
  u32 tr[8][4][2];
#pragma unroll
  for(int jt = 0; jt < 8; ++jt)
#pragma unroll
    for(int st = 0; st < 4; ++st){
      tr[jt][st][0] = pk2(fmaxf(acc1[jt][st][0], 0.f), fmaxf(acc1[jt][st][1], 0.f));
      tr[jt][st][1] = pk2(fmaxf(acc1[jt][st][2], 0.f), fmaxf(acc1[jt][st][3], 0.f));
    }
  fence();

  // ---- mid2 (permuted k-map; B = own tr; A = 1x b128) + stage-4 fold ----
  float p0 = 0.f, p1 = 0.f, p2 = 0.f, p3 = 0.f;
#pragma unroll
  for(int jt = 0; jt < 8; ++jt){
    const int j = lm + 16 * jt;
    const u32 sz = (u32)((j & 7) << 2);
    const u32* r = W3lds + j * 64;
    const float4 bc = *(const float4*)(b3 + jt * 16 + lg * 4);
    const f32x4 cinit = {bc.x, bc.y, bc.z, bc.w};
    f32x4 a0 = cinit, a1 = cinit, a2 = cinit, a3 = cinit;
#pragma unroll
    for(int kt = 0; kt < 4; ++kt){
      bf16x8 av = __builtin_bit_cast(bf16x8,
          *(const uint4*)(r + (((u32)(kt * 16 + lg * 4)) ^ sz)));
      uint4 q0; q0.x = tr[2*kt][0][0]; q0.y = tr[2*kt][0][1];
      q0.z = tr[2*kt+1][0][0]; q0.w = tr[2*kt+1][0][1];
      uint4 q1; q1.x = tr[2*kt][1][0]; q1.y = tr[2*kt][1][1];
      q1.z = tr[2*kt+1][1][0]; q1.w = tr[2*kt+1][1][1];
      uint4 q2; q2.x = tr[2*kt][2][0]; q2.y = tr[2*kt][2][1];
      q2.z = tr[2*kt+1][2][0]; q2.w = tr[2*kt+1][2][1];
      uint4 q3; q3.x = tr[2*kt][3][0]; q3.y = tr[2*kt][3][1];
      q3.z = tr[2*kt+1][3][0]; q3.w = tr[2*kt+1][3][1];
      a0 = __builtin_amdgcn_mfma_f32_16x16x32_bf16(av, __builtin_bit_cast(bf16x8, q0), a0, 0, 0, 0);
      a1 = __builtin_amdgcn_mfma_f32_16x16x32_bf16(av, __builtin_bit_cast(bf16x8, q1), a1, 0, 0, 0);
      a2 = __builtin_amdgcn_mfma_f32_16x16x32_bf16(av, __builtin_bit_cast(bf16x8, q2), a2, 0, 0, 0);
      a3 = __builtin_amdgcn_mfma_f32_16x16x32_bf16(av, __builtin_bit_cast(bf16x8, q3), a3, 0, 0, 0);
    }
    const float4 wc = *(const float4*)(W4 + jt * 16 + lg * 4);
    p0 = fmaf(fmaxf(a0[0], 0.f), wc.x, p0); p0 = fmaf(fmaxf(a0[1], 0.f), wc.y, p0);
    p0 = fmaf(fmaxf(a0[2], 0.f), wc.z, p0); p0 = fmaf(fmaxf(a0[3], 0.f), wc.w, p0);
    p1 = fmaf(fmaxf(a1[0], 0.f), wc.x, p1); p1 = fmaf(fmaxf(a1[1], 0.f), wc.y, p1);
    p1 = fmaf(fmaxf(a1[2], 0.f), wc.z, p1); p1 = fmaf(fmaxf(a1[3], 0.f), wc.w, p1);
    p2 = fmaf(fmaxf(a2[0], 0.f), wc.x, p2); p2 = fmaf(fmaxf(a2[1], 0.f), wc.y, p2);
    p2 = fmaf(fmaxf(a2[2], 0.f), wc.z, p2); p2 = fmaf(fmaxf(a2[3], 0.f), wc.w, p2);
    p3 = fmaf(fmaxf(a3[0], 0.f), wc.x, p3); p3 = fmaf(fmaxf(a3[1], 0.f), wc.y, p3);
    p3 = fmaf(fmaxf(a3[2], 0.f), wc.z, p3); p3 = fmaf(fmaxf(a3[3], 0.f), wc.w, p3);
  }
  fence();
  p0 += __shfl_xor(p0, 16, 64); p0 += __shfl_xor(p0, 32, 64);
  p1 += __shfl_xor(p1, 16, 64); p1 += __shfl_xor(p1, 32, 64);
  p2 += __shfl_xor(p2, 16, 64); p2 += __shfl_xor(p2, 32, 64);
  p3 += __shfl_xor(p3, 16, 64); p3 += __shfl_xor(p3, 32, 64);
  return (lg == 0) ? p0 : (lg == 1) ? p1 : (lg == 2) ? p2 : p3;
}

// ---------------- preprocess: fp32 weights -> bf16 LDS-image in d_ws ----------------
// 32 blocks x 256 threads. Slab b (8192 dwords): layer = b>>2, which = b&3
// (0: sW2 natural, 1: sW3 permuted, 2: tW2 natural, 3: tW3 permuted).
extern "C" __global__ void __launch_bounds__(256)
prep_kernel(const float* __restrict__ sW2, const float* __restrict__ sW3,
            const float* __restrict__ tW2, const float* __restrict__ tW3,
            u32* __restrict__ ws)
{
  const int b = blockIdx.x;
  const int layer = b >> 2, which = b & 3;
  const float* src = (which == 0 ? sW2 : which == 1 ? sW3 : which == 2 ? tW2 : tW3)
                     + layer * (WD * WD);
  u32* dst = ws + b * 8192;
  if(which & 1) stage_Wperm(src, dst, threadIdx.x);
  else          stage_Wnat (src, dst, threadIdx.x);
}

// ---------------- main kernel: double-buffered DMA staging ----------------
extern "C" __global__ void __launch_bounds__(512)
flow_dma(const float* __restrict__ x, const float* __restrict__ s_scale,
         const float* __restrict__ sW1, const float* __restrict__ sb1,
         const float* __restrict__ sb2, const float* __restrict__ sb3,
         const float* __restrict__ sW4, const float* __restrict__ sb4,
         const float* __restrict__ tW1, const float* __restrict__ tb1,
         const float* __restrict__ tb2, const float* __restrict__ tb3,
         const float* __restrict__ tW4, const float* __restrict__ tb4,
         const u32* __restrict__ wimg, float* __restrict__ out)
{
  __shared__ u32 Wbuf[2][16384];   // 128 KB: [buf][W2(8192) | W3(8192)]

  const int tid = threadIdx.x;
  const int lane = tid & 63, lg = lane >> 4, lm = lane & 15, wv = tid >> 6;
  const int gs = (int)blockIdx.x * 512 + tid;

  float2 ab = ((const float2*)x)[gs];
  float* scat = out + 2 * BATCH;
  float sv = 0.f;

  stage_dma(wimg, Wbuf[0], wv, lane);          // phase 0 slab

#pragma unroll 1
  for(int ph = 0; ph < 2 * LNUM; ++ph){
    const int i = ph >> 1, isT = ph & 1, parity = i & 1;
    asm volatile("s_waitcnt vmcnt(0)" ::: "memory");
    __syncthreads();                            // Wbuf[ph&1] fully landed
    if(ph < 2 * LNUM - 1)
      stage_dma(wimg + (size_t)(ph + 1) * 16384, Wbuf[(ph + 1) & 1], wv, lane);

    const int off = i * WD;
    const float u = parity ? ab.y : ab.x;
    const u32* W2l = Wbuf[ph & 1];
    const u32* W3l = Wbuf[ph & 1] + 8192;

    if(!isT){
      float pre = mlp_full(u, W2l, W3l, sW1 + off, sb1 + off,
                           sb2 + off, sb3 + off, sW4 + off, lm, lg) + sb4[i];
      sv = s_scale[i] * tanhf(pre);
      scat[i * BATCH + gs] = sv;
    } else {
      float pre = mlp_full(u, W2l, W3l, tW1 + off, tb1 + off,
                           tb2 + off, tb3 + off, tW4 + off, lm, lg) + tb4[i];
      const float tv = tanhf(pre);
      const float e = expf(sv);
      if(parity) ab.x = e * ab.x + tv; else ab.y = e * ab.y + tv;
    }
  }

  ((float2*)out)[gs] = ab;
}

// ---------------- fallback: inline staging (R10 structure) ----------------
extern "C" __global__ void __launch_bounds__(256, 2)
flow_fb(const float* __restrict__ x, const float* __restrict__ s_scale,
        const float* __restrict__ sW1, const float* __restrict__ sb1,
        const float* __restrict__ sW2, const float* __restrict__ sb2,
        const float* __restrict__ sW3, const float* __restrict__ sb3,
        const float* __restrict__ sW4, const float* __restrict__ sb4,
        const float* __restrict__ tW1, const float* __restrict__ tb1,
        const float* __restrict__ tW2, const float* __restrict__ tb2,
        const float* __restrict__ tW3, const float* __restrict__ tb3,
        const float* __restrict__ tW4, const float* __restrict__ tb4,
        float* __restrict__ out)
{
  __shared__ u32 Wlds[2][8192];

  const int tid = threadIdx.x;
  const int lane = tid & 63, lg = lane >> 4, lm = lane & 15;
  const int gs = (int)blockIdx.x * 256 + tid;

  float2 ab = ((const float2*)x)[gs];
  float* scat = out + 2 * BATCH;

#pragma unroll 1
  for(int i = 0; i < LNUM; ++i){
    const int parity = i & 1;
    const float sc = s_scale[i];
    const int off = i * WD, offW = i * (WD * WD);

    __syncthreads();
    stage_Wnat (sW2 + offW, Wlds[0], tid);
    stage_Wperm(sW3 + offW, Wlds[1], tid);
    __syncthreads();
    const float u = parity ? ab.y : ab.x;
    float preS = mlp_full(u, Wlds[0], Wlds[1], sW1 + off, sb1 + off,
                          sb2 + off, sb3 + off, sW4 + off, lm, lg) + sb4[i];
    const float sv = sc * tanhf(preS);
    scat[i * BATCH + gs] = sv;

    __syncthreads();
    stage_Wnat (tW2 + offW, Wlds[0], tid);
    stage_Wperm(tW3 + offW, Wlds[1], tid);
    __syncthreads();
    float preT = mlp_full(u, Wlds[0], Wlds[1], tW1 + off, tb1 + off,
                          tb2 + off, tb3 + off, tW4 + off, lm, lg) + tb4[i];
    const float tv = tanhf(preT);
    const float e = expf(sv);
    if(parity) ab.x = e * ab.x + tv; else ab.y = e * ab.y + tv;
  }

  ((float2*)out)[gs] = ab;
}

extern "C" void kernel_launch(void* const* d_in, const int* in_sizes, int n_in,
                              void* d_out, int out_size, void* d_ws, size_t ws_size,
                              hipStream_t stream) {
  (void)in_sizes; (void)n_in; (void)out_size;
  const float* p[18];
  for(int k = 0; k < 18; ++k) p[k] = (const float*)d_in[k];

  const size_t need = (size_t)32 * 8192 * 4;   // 1 MiB bf16 weight image
  if(ws_size >= need){
    u32* ws = (u32*)d_ws;
    hipLaunchKernelGGL(prep_kernel, dim3(32), dim3(256), 0, stream,
                       p[4], p[6], p[12], p[14], ws);
    hipLaunchKernelGGL(flow_dma, dim3(BATCH / 512), dim3(512), 0, stream,
                       p[0], p[1], p[2], p[3], p[5], p[7], p[8], p[9],
                       p[10], p[11], p[13], p[15], p[16], p[17],
                       (const u32*)ws, (float*)d_out);
  } else {
    hipLaunchKernelGGL(flow_fb, dim3(BATCH / 256), dim3(256), 0, stream,
                       p[0], p[1], p[2], p[3], p[4], p[5], p[6], p[7], p[8], p[9],
                       p[10], p[11], p[12], p[13], p[14], p[15], p[16], p[17],
                       (float*)d_out);
  }
}